// Round 3
// baseline (8015.965 us; speedup 1.0000x reference)
//
#include <hip/hip_runtime.h>

// 2-layer LSTM LM. V=5000 H=1024 E=512 B=64 T=256, future=0.
// Round-3 structure (robustness first — no cooperative launch, no spin barriers):
//   1. pack kernels: fp32->bf16 weights (gate-interleaved rows) + embedding
//      gather -> staged in the TAIL OF d_out (dead before gemm_out runs).
//   2. 257 launches of step_k(t): blocks 0..127 = layer1 step t,
//      blocks 128..255 = layer2 step t-1. Kernel boundaries give ordering.
//   3. one big MFMA GEMM (16384 x 5120pad x 1024) for the output linear;
//      lin_W converted fp32->bf16 on the fly (no packed copy needed).
// d_ws usage: ONLY h2a = (T+1)*B*H bf16 = 33.69 MB.

#define V_ 5000
#define H_ 1024
#define E_ 512
#define B_ 64
#define T_ 256

// float-element offsets into d_out for staging that is dead before gemm_out.
// out_size = B*T*V = 81,920,000 floats; regions below fit exactly at the tail.
#define OFF_W1P  70180864   // 6,291,456 bf16  (4096x1536)
#define OFF_W2P  73326592   // 8,388,608 bf16  (4096x2048)
#define OFF_XEMB 77520896   // 8,388,608 bf16  (T*B*E)
#define OFF_H1B  81715200   // 131,072 bf16    (2 x B x H double buffer)
#define OFF_C1   81780736   // 65,536 fp32
#define OFF_C2   81846272   // 65,536 fp32
#define OFF_B1P  81911808   // 4,096 fp32
#define OFF_B2P  81915904   // 4,096 fp32      (ends exactly at 81,920,000)

typedef unsigned short ushort_t;
typedef __bf16 bf16x8 __attribute__((ext_vector_type(8)));
typedef unsigned short us8 __attribute__((ext_vector_type(8)));
typedef float f32x4 __attribute__((ext_vector_type(4)));

__device__ __forceinline__ ushort_t f2bf(float f) {  // RNE fp32->bf16
  unsigned int u = __float_as_uint(f);
  u += 0x7fffu + ((u >> 16) & 1u);
  return (ushort_t)(u >> 16);
}

__device__ __forceinline__ f32x4 mfma16(us8 a, us8 b, f32x4 c) {
  return __builtin_amdgcn_mfma_f32_16x16x32_bf16(
      __builtin_bit_cast(bf16x8, a), __builtin_bit_cast(bf16x8, b), c, 0, 0, 0);
}

__device__ __forceinline__ float sig_(float x) { return 1.f / (1.f + __expf(-x)); }
__device__ __forceinline__ float tanh_(float x) { return 2.f / (1.f + __expf(-2.f * x)) - 1.f; }

// ---------------- prep kernels ----------------

__global__ void zero_init(ushort_t* h1buf, float* c1, float* c2, ushort_t* h2s0) {
  int i = blockIdx.x * 256 + threadIdx.x;     // grid 512*256 = 131072
  if (i < 2 * B_ * H_) h1buf[i] = 0;
  if (i < B_ * H_) { c1[i] = 0.f; c2[i] = 0.f; h2s0[i] = 0; }
}

// packed row p: blk=p>>5 owns units blk*8..+7; rl=p&31 = tile*16 + half*8 + (u&7),
// gate g = tile*2+half (0=i 1=f 2=g 3=o). Layer1 cols: [0,1024)=W_hh1, [1024,1536)=W_ih1.
__global__ void pack_w1(const float* __restrict__ Whh, const float* __restrict__ Wih,
                        const float* __restrict__ bi, const float* __restrict__ bh,
                        ushort_t* __restrict__ W1p, float* __restrict__ b1p) {
  int p = blockIdx.x;
  int rl = p & 31, blk = p >> 5;
  int g = ((rl >> 4) << 1) | ((rl >> 3) & 1);
  int u = (blk << 3) | (rl & 7);
  int sr = g * 1024 + u;
  for (int k = threadIdx.x; k < 1536; k += 256) {
    float v = (k < 1024) ? Whh[sr * 1024 + k] : Wih[sr * 512 + (k - 1024)];
    W1p[p * 1536 + k] = f2bf(v);
  }
  if (threadIdx.x == 0) b1p[p] = bi[sr] + bh[sr];
}

// Layer2 cols: [0,1024)=W_ih2 (input h1_t), [1024,2048)=W_hh2 (h2_{t-1}).
__global__ void pack_w2(const float* __restrict__ Wih, const float* __restrict__ Whh,
                        const float* __restrict__ bi, const float* __restrict__ bh,
                        ushort_t* __restrict__ W2p, float* __restrict__ b2p) {
  int p = blockIdx.x;
  int rl = p & 31, blk = p >> 5;
  int g = ((rl >> 4) << 1) | ((rl >> 3) & 1);
  int u = (blk << 3) | (rl & 7);
  int sr = g * 1024 + u;
  for (int k = threadIdx.x; k < 2048; k += 256) {
    float v = (k < 1024) ? Wih[sr * 1024 + k] : Whh[sr * 1024 + (k - 1024)];
    W2p[p * 2048 + k] = f2bf(v);
  }
  if (threadIdx.x == 0) b2p[p] = bi[sr] + bh[sr];
}

__global__ void embed_k(const int* __restrict__ inp, const float* __restrict__ emb,
                        ushort_t* __restrict__ xemb) {
  int tb = blockIdx.x;           // tb = t*64 + b
  int t = tb >> 6, b = tb & 63;
  int tok = inp[b * T_ + t];
  const float* src = emb + (long)tok * E_;
  ushort_t* dst = xemb + (long)tb * E_;
  for (int k = threadIdx.x; k < E_; k += 256) dst[k] = f2bf(src[k]);
}

// ---------------- per-timestep kernel (launched 257 times) ----------------
// blocks 0..127: layer1 step t (if t < T); blocks 128..255: layer2 step t-1 (if t >= 1)

__global__ __launch_bounds__(256) void step_k(const ushort_t* __restrict__ W1p,
                                              const ushort_t* __restrict__ W2p,
                                              const float* __restrict__ b1p,
                                              const float* __restrict__ b2p,
                                              const ushort_t* __restrict__ xemb,
                                              ushort_t* __restrict__ h1buf,
                                              float* __restrict__ c1,
                                              float* __restrict__ c2,
                                              ushort_t* __restrict__ h2a,
                                              int t) {
  int tid = threadIdx.x, wave = tid >> 6, lane = tid & 63;
  int quad = lane >> 4, col = lane & 15;
  int bx = blockIdx.x;
  int m0 = wave * 16;
  bool lower = (col & 8) == 0;

  if (bx < 128) {
    if (t >= T_) return;  // ---- layer1, step t ----
    const ushort_t* h1prev = h1buf + (t & 1) * (B_ * H_);
    ushort_t* h1next = h1buf + ((t + 1) & 1) * (B_ * H_);
    const ushort_t* xt = xemb + t * (B_ * E_);
    int blk = bx, j0 = blk * 8;
    int m = m0 + col;
    const ushort_t* ar = h1prev + m * H_ + quad * 8;
    const ushort_t* xr = xt + m * E_ + quad * 8;
    const ushort_t* w0 = W1p + (blk * 32 + col) * 1536 + quad * 8;
    const ushort_t* w1 = w0 + 16 * 1536;
    f32x4 acc0 = {0.f, 0.f, 0.f, 0.f}, acc1 = {0.f, 0.f, 0.f, 0.f};
#pragma unroll 8
    for (int ki = 0; ki < 48; ++ki) {
      us8 av = (ki < 32) ? *(const us8*)(ar + ki * 32)
                         : *(const us8*)(xr + (ki - 32) * 32);
      acc0 = mfma16(av, *(const us8*)(w0 + ki * 32), acc0);
      acc1 = mfma16(av, *(const us8*)(w1 + ki * 32), acc1);
    }
    float bias0 = b1p[blk * 32 + col];
    float bias1 = b1p[blk * 32 + 16 + col];
    int u = j0 + (col & 7);
#pragma unroll
    for (int r = 0; r < 4; ++r) {
      float p0 = acc0[r] + bias0, p1 = acc1[r] + bias1;
      float q0 = __shfl_xor(p0, 8), q1 = __shfl_xor(p1, 8);
      if (lower) {  // p0=i, q0=f, p1=g, q1=o
        int mm = m0 + quad * 4 + r;
        float cold = c1[mm * H_ + u];
        float cn = sig_(q0) * cold + sig_(p0) * tanh_(p1);
        c1[mm * H_ + u] = cn;
        h1next[mm * H_ + u] = f2bf(sig_(q1) * tanh_(cn));
      }
    }
  } else {
    if (t < 1) return;  // ---- layer2, step t2 = t-1 ----
    int t2 = t - 1;
    const ushort_t* h1cur = h1buf + ((t2 + 1) & 1) * (B_ * H_);
    const ushort_t* h2prev = h2a + t2 * (B_ * H_);
    ushort_t* h2next = h2a + (t2 + 1) * (B_ * H_);
    int blk = bx - 128, j0 = blk * 8;
    int m = m0 + col;
    const ushort_t* ar = h1cur + m * H_ + quad * 8;
    const ushort_t* hr = h2prev + m * H_ + quad * 8;
    const ushort_t* w0 = W2p + (blk * 32 + col) * 2048 + quad * 8;
    const ushort_t* w1 = w0 + 16 * 2048;
    f32x4 acc0 = {0.f, 0.f, 0.f, 0.f}, acc1 = {0.f, 0.f, 0.f, 0.f};
#pragma unroll 8
    for (int ki = 0; ki < 64; ++ki) {
      us8 av = (ki < 32) ? *(const us8*)(ar + ki * 32)
                         : *(const us8*)(hr + (ki - 32) * 32);
      acc0 = mfma16(av, *(const us8*)(w0 + ki * 32), acc0);
      acc1 = mfma16(av, *(const us8*)(w1 + ki * 32), acc1);
    }
    float bias0 = b2p[blk * 32 + col];
    float bias1 = b2p[blk * 32 + 16 + col];
    int u = j0 + (col & 7);
#pragma unroll
    for (int r = 0; r < 4; ++r) {
      float p0 = acc0[r] + bias0, p1 = acc1[r] + bias1;
      float q0 = __shfl_xor(p0, 8), q1 = __shfl_xor(p1, 8);
      if (lower) {
        int mm = m0 + quad * 4 + r;
        float cold = c2[mm * H_ + u];
        float cn = sig_(q0) * cold + sig_(p0) * tanh_(p1);
        c2[mm * H_ + u] = cn;
        h2next[mm * H_ + u] = f2bf(sig_(q1) * tanh_(cn));
      }
    }
  }
}

// ------- output linear GEMM: C(16384 x 5120pad) = h2_all * lin_W^T + lin_b -------
// A = h2a slots 1..T (bf16, row m = t*64+b). B = lin_W fp32, converted on the fly.

__global__ __launch_bounds__(256) void gemm_out(const ushort_t* __restrict__ h2a,
                                                const float* __restrict__ linW,
                                                const float* __restrict__ linb,
                                                float* __restrict__ out) {
  __shared__ ushort_t As[128 * 40];  // stride 40 elems (80B): <=2-way LDS aliasing
  __shared__ ushort_t Bs[128 * 40];
  int tid = threadIdx.x;
  int wave = tid >> 6, lane = tid & 63, quad = lane >> 4, col = lane & 15;
  int bm = blockIdx.x & 127, bn = blockIdx.x >> 7;
  int wm = (wave & 1) * 64, wn = (wave >> 1) * 64;
  const ushort_t* Ag = h2a + B_ * H_;  // skip zero slot: row m = t*64+b

  f32x4 acc[4][4];
#pragma unroll
  for (int i = 0; i < 4; ++i)
#pragma unroll
    for (int j = 0; j < 4; ++j) acc[i][j] = f32x4{0.f, 0.f, 0.f, 0.f};

  int arow = tid >> 1, koff = (tid & 1) * 16;
  const ushort_t* ag = Ag + (bm * 128 + arow) * 1024 + koff;
  int brow = bn * 128 + arow;
  const float* bgf = linW + (long)brow * 1024 + koff;
  bool bvalid = (brow < V_);

  for (int kt = 0; kt < 32; ++kt) {
    int k0 = kt * 32;
    us8 a0 = *(const us8*)(ag + k0);
    us8 a1 = *(const us8*)(ag + k0 + 8);
    us8 b0, b1;
    if (bvalid) {
      f32x4 q0 = *(const f32x4*)(bgf + k0);
      f32x4 q1 = *(const f32x4*)(bgf + k0 + 4);
      f32x4 q2 = *(const f32x4*)(bgf + k0 + 8);
      f32x4 q3 = *(const f32x4*)(bgf + k0 + 12);
#pragma unroll
      for (int j = 0; j < 4; ++j) {
        b0[j] = f2bf(q0[j]); b0[j + 4] = f2bf(q1[j]);
        b1[j] = f2bf(q2[j]); b1[j + 4] = f2bf(q3[j]);
      }
    } else {
      b0 = us8{0, 0, 0, 0, 0, 0, 0, 0};
      b1 = us8{0, 0, 0, 0, 0, 0, 0, 0};
    }
    *(us8*)(As + arow * 40 + koff) = a0;
    *(us8*)(As + arow * 40 + koff + 8) = a1;
    *(us8*)(Bs + arow * 40 + koff) = b0;
    *(us8*)(Bs + arow * 40 + koff + 8) = b1;
    __syncthreads();
    us8 af[4], bf[4];
#pragma unroll
    for (int mi = 0; mi < 4; ++mi)
      af[mi] = *(const us8*)(As + (wm + mi * 16 + col) * 40 + quad * 8);
#pragma unroll
    for (int ni = 0; ni < 4; ++ni)
      bf[ni] = *(const us8*)(Bs + (wn + ni * 16 + col) * 40 + quad * 8);
#pragma unroll
    for (int mi = 0; mi < 4; ++mi)
#pragma unroll
      for (int ni = 0; ni < 4; ++ni) acc[mi][ni] = mfma16(af[mi], bf[ni], acc[mi][ni]);
    __syncthreads();
  }

#pragma unroll
  for (int mi = 0; mi < 4; ++mi) {
    int mgb = bm * 128 + wm + mi * 16 + quad * 4;
#pragma unroll
    for (int ni = 0; ni < 4; ++ni) {
      int ng = bn * 128 + wn + ni * 16 + col;
      if (ng < V_) {
        float lb = linb[ng];
#pragma unroll
        for (int r = 0; r < 4; ++r) {
          int m = mgb + r;          // m = t*64 + b
          int t = m >> 6, b = m & 63;
          out[b * (T_ * V_) + t * V_ + ng] = acc[mi][ni][r] + lb;
        }
      }
    }
  }
}

// ---------------- launch ----------------

extern "C" void kernel_launch(void* const* d_in, const int* in_sizes, int n_in,
                              void* d_out, int out_size, void* d_ws, size_t ws_size,
                              hipStream_t stream) {
  const int* inp = (const int*)d_in[0];
  // d_in[1] = future (always 0) — ignored
  const float* embW = (const float*)d_in[2];
  const float* Wih1 = (const float*)d_in[3];
  const float* Whh1 = (const float*)d_in[4];
  const float* bih1 = (const float*)d_in[5];
  const float* bhh1 = (const float*)d_in[6];
  const float* Wih2 = (const float*)d_in[7];
  const float* Whh2 = (const float*)d_in[8];
  const float* bih2 = (const float*)d_in[9];
  const float* bhh2 = (const float*)d_in[10];
  const float* linW = (const float*)d_in[11];
  const float* linb = (const float*)d_in[12];
  float* out = (float*)d_out;

  // staging in the tail of d_out (all dead before gemm_out writes d_out)
  ushort_t* W1p  = (ushort_t*)(out + OFF_W1P);
  ushort_t* W2p  = (ushort_t*)(out + OFF_W2P);
  ushort_t* xemb = (ushort_t*)(out + OFF_XEMB);
  ushort_t* h1b  = (ushort_t*)(out + OFF_H1B);
  float*    c1   = out + OFF_C1;
  float*    c2   = out + OFF_C2;
  float*    b1p  = out + OFF_B1P;
  float*    b2p  = out + OFF_B2P;

  // workspace: ONLY h2a (33.69 MB), which must be live during gemm_out
  ushort_t* h2a = (ushort_t*)d_ws;

  zero_init<<<512, 256, 0, stream>>>(h1b, c1, c2, h2a);
  pack_w1<<<4096, 256, 0, stream>>>(Whh1, Wih1, bih1, bhh1, W1p, b1p);
  pack_w2<<<4096, 256, 0, stream>>>(Wih2, Whh2, bih2, bhh2, W2p, b2p);
  embed_k<<<T_ * B_, 256, 0, stream>>>(inp, embW, xemb);

  for (int t = 0; t <= T_; ++t)
    step_k<<<256, 256, 0, stream>>>(W1p, W2p, b1p, b2p, xemb, h1b, c1, c2, h2a, t);

  gemm_out<<<128 * 40, 256, 0, stream>>>(h2a, linW, linb, out);
}